// Round 14
// baseline (1145.720 us; speedup 1.0000x reference)
//
#include <hip/hip_runtime.h>
#include <math.h>

#define VOCAB 10000
#define VPAD  10240   // padded so fc n-tile -> XCD map is stable (bid%8)
#define EMBED 256
#define ENC   2048
#define DEC   512
#define ATT   512
#define B_    64
#define P_    49
#define T_    30
#define G4    2048   // 4*DEC
#define SL    32768  // one state slice = B_*DEC (= 64*512)
#define NGEMM 2920   // mega_k: GEMM blocks (392 + 960 + 1568)
#define NPREP 1080   // mega_k: grid-stride prep blocks

typedef __bf16 bf16_t;
typedef bf16_t bf16x8 __attribute__((ext_vector_type(8)));
typedef float  f32x4  __attribute__((ext_vector_type(4)));

__device__ __forceinline__ float sigf(float x) { return 1.f / (1.f + expf(-x)); }

// ===========================================================================
// MEGA NODE: prep (grid-stride, bids >= NGEMM) + the three bulk GEMMs
// (bids < NGEMM), fused so prep's pure memory traffic overlaps GEMM compute.
// GEMM segments read ONLY harness inputs (seg1 gathers emb inline; biases
// read directly) -> no intra-kernel ordering hazards.
// Packings (verified r5-r13):
//  fp1h[((nb*16+kf)*4+s)*512+l*8+j] = W_hh1[s*512+nb*16+(l&15)][kf*32+(l>>4)*8+j]
//  fp2 same with 32 kf (kf<16: Wih2, kf>=16: Whh2).
//  W2sp[((nb*32+nt)*64+lq)*8+j]: B-frag of W2 col-strip nb, K=32 zero-padded.
// Zeroed per call: h1s/h2s slice0, c slices, hwp, G1h.
// ===========================================================================
struct MegaP {
    // inputs
    const float *features, *emb, *W1, *b1, *W2, *W_ih1, *W_hh1, *W_ih2, *W_hh2;
    const float *b_ih1, *b_hh1, *b_ih2, *b_hh2, *fc_W;
    const int* caps;
    // outputs
    bf16_t *fW1b, *xembb, *F1g, *W2sp, *fp1h, *fp2, *fcWb;
    float *bsum2, *hwp, *G1h, *c1s0, *c2s0;
    bf16_t *h1s0, *h2s0;
};

__global__ __launch_bounds__(256) void mega_k(MegaP p)
{
    const int bid = blockIdx.x;
    const int tid = threadIdx.x;

    if (bid >= NGEMM) {
        // ---------------- prep segment (r13-verified loops) ----------------
        long stride = (long)NPREP * 256;
        long i0 = (long)(bid - NGEMM) * 256 + tid;
        for (long i = i0; i < SL; i += stride) {
            p.h1s0[i] = (bf16_t)0.f; p.h2s0[i] = (bf16_t)0.f;
            p.c1s0[i] = 0.f; p.c2s0[i] = 0.f;
        }
        for (long i = i0; i < 32L * SL; i += stride) p.hwp[i] = 0.f;
        for (long i = i0; i < 64L * 2048; i += stride) p.G1h[i] = 0.f;
        for (long i = i0; i < 2048; i += stride)
            p.bsum2[i] = p.b_ih2[i] + p.b_hh2[i];
        for (long i = i0; i < 32L * 32 * 64 * 8; i += stride) {  // W2sp (1 MB)
            long j8 = i & 7, lq = (i >> 3) & 63, nt = (i >> 9) & 31, nb = i >> 14;
            long k = (lq >> 4) * 8 + j8;
            long a = nt * 16 + (lq & 15);
            p.W2sp[i] = (bf16_t)(k < 16 ? p.W2[a * 512 + nb * 16 + k] : 0.f);
        }
        for (long i = i0; i < 32L * 16 * 2048; i += stride) { // fp1h (Whh1)
            long j8 = i & 7, lq = (i >> 3) & 63, s = (i >> 9) & 3, nk = i >> 11;
            long kf = nk & 15, nb = nk >> 4;
            long c = s * 512 + nb * 16 + (lq & 15);
            long k = kf * 32 + (lq >> 4) * 8 + j8;
            p.fp1h[i] = (bf16_t)p.W_hh1[c * 512 + k];
        }
        for (long i = i0; i < 2048L * 1024; i += stride) { // fp2
            long j8 = i & 7, lq = (i >> 3) & 63, s = (i >> 9) & 3, nk = i >> 11;
            long kf = nk & 31, nb = nk >> 5;
            long c = s * 512 + nb * 16 + (lq & 15);
            long k = kf * 32 + (lq >> 4) * 8 + j8;
            p.fp2[i] = (bf16_t)(k < 512 ? p.W_ih2[c * 512 + k] : p.W_hh2[c * 512 + (k - 512)]);
        }
        for (long i = i0; i < (long)VPAD * 512; i += stride) {
            long r = i >> 9;
            p.fcWb[i] = (bf16_t)(r < VOCAB ? p.fc_W[i] : 0.f);
        }
        return;
    }

    // ---------------- GEMM segments (r13-verified mm3 body) ----------------
    //  seg0 (392):  fW1b  = features(f32) @ W1^T + b1            M=3136 N=512  K=2048
    //  seg1 (960):  xembb = gather(emb)(f32) @ Wih1[:,:256]^T
    //               + (b_ih1+b_hh1)                              M=1920 N=2048 K=256
    //  seg2 (1568): F1g   = features(f32) @ Wih1[:,256:]^T       M=3136 N=2048 K=2048
    int seg; const float* Af; int lda;
    const float* Bw; int ldb, boff;
    bf16_t* outB; int ldo, K, bn, bm;
    if (bid < 392) {
        seg = 0; Af = p.features; lda = ENC; Bw = p.W1; ldb = ENC; boff = 0;
        outB = p.fW1b; ldo = ATT; K = ENC;
        bn = (bid & 7) * 64; bm = (bid >> 3) * 64;
    } else if (bid < 1352) {
        int b2i = bid - 392;
        seg = 1; Af = nullptr; lda = 0; Bw = p.W_ih1; ldb = EMBED + ENC; boff = 0;
        outB = p.xembb; ldo = G4; K = EMBED;
        bn = (b2i & 31) * 64; bm = (b2i >> 5) * 64;
    } else {
        int b3i = bid - 1352;
        seg = 2; Af = p.features; lda = ENC; Bw = p.W_ih1; ldb = EMBED + ENC; boff = EMBED;
        outB = p.F1g; ldo = G4; K = ENC;
        bn = (b3i & 31) * 64; bm = (b3i >> 5) * 64;
    }

    __shared__ bf16_t Apad[64][72];
    __shared__ bf16_t Bpad[64][72];
    const int w = tid >> 6, l = tid & 63;
    f32x4 acc[4] = {};

    for (int k0 = 0; k0 < K; k0 += 64) {
        for (int c = tid; c < 512; c += 256) {
            int row = c >> 3, q = c & 7;
            const float* as;
            if (seg == 1) {
                int m = bm + row;                       // global m row = t*64+b
                int tq = m >> 6, b = m & 63;
                int cap = p.caps[b * T_ + tq];
                as = &p.emb[(size_t)cap * 256 + k0 + q * 8];
            } else {
                as = &Af[(size_t)(bm + row) * lda + k0 + q * 8];
            }
            {
                float4 f0 = *(const float4*)as;
                float4 f1 = *(const float4*)(as + 4);
                bf16x8 v;
                v[0] = (bf16_t)f0.x; v[1] = (bf16_t)f0.y; v[2] = (bf16_t)f0.z; v[3] = (bf16_t)f0.w;
                v[4] = (bf16_t)f1.x; v[5] = (bf16_t)f1.y; v[6] = (bf16_t)f1.z; v[7] = (bf16_t)f1.w;
                *(bf16x8*)&Apad[row][q * 8] = v;
            }
            const float* bs = &Bw[(size_t)(bn + row) * ldb + boff + k0 + q * 8];
            float4 f0 = *(const float4*)bs;
            float4 f1 = *(const float4*)(bs + 4);
            bf16x8 v;
            v[0] = (bf16_t)f0.x; v[1] = (bf16_t)f0.y; v[2] = (bf16_t)f0.z; v[3] = (bf16_t)f0.w;
            v[4] = (bf16_t)f1.x; v[5] = (bf16_t)f1.y; v[6] = (bf16_t)f1.z; v[7] = (bf16_t)f1.w;
            *(bf16x8*)&Bpad[row][q * 8] = v;
        }
        __syncthreads();
#pragma unroll
        for (int ks = 0; ks < 2; ++ks) {
            bf16x8 a8 = *(const bf16x8*)&Apad[w * 16 + (l & 15)][ks * 32 + (l >> 4) * 8];
#pragma unroll
            for (int nf = 0; nf < 4; ++nf) {
                bf16x8 b8 = *(const bf16x8*)&Bpad[nf * 16 + (l & 15)][ks * 32 + (l >> 4) * 8];
                acc[nf] = __builtin_amdgcn_mfma_f32_16x16x32_bf16(a8, b8, acc[nf], 0, 0, 0);
            }
        }
        __syncthreads();
    }

    int rbase = bm + w * 16 + (l >> 4) * 4;
    int cl = l & 15;
#pragma unroll
    for (int nf = 0; nf < 4; ++nf) {
        int col = bn + nf * 16 + cl;
        float bv = (seg == 0) ? p.b1[col]
                 : (seg == 1) ? (p.b_ih1[col] + p.b_hh1[col]) : 0.f;
#pragma unroll
        for (int j = 0; j < 4; ++j)
            outB[(size_t)(rbase + j) * ldo + col] = (bf16_t)(acc[nf][j] + bv);
    }
}

// ---------------------------------------------------------------------------
// fc GEMM (bf16 A/B, f32 out, row remap + N guard) — verified r6-r13.
// ---------------------------------------------------------------------------
__global__ __launch_bounds__(256) void mm_fc(
    const bf16_t* __restrict__ A, int lda,
    const bf16_t* __restrict__ Bw, int ldb,
    const float* __restrict__ bias,
    float* __restrict__ outF, int ldo, int N, int K)
{
    __shared__ bf16_t Apad[64][72];
    __shared__ bf16_t Bpad[64][72];
    const int bn = blockIdx.x * 64, bm = blockIdx.y * 64;
    const int tid = threadIdx.x;
    const int w = tid >> 6, l = tid & 63;
    f32x4 acc[4] = {};

    for (int k0 = 0; k0 < K; k0 += 64) {
        for (int c = tid; c < 512; c += 256) {
            int row = c >> 3, q = c & 7;
            *(bf16x8*)&Apad[row][q * 8] = *(const bf16x8*)&A[(size_t)(bm + row) * lda + k0 + q * 8];
            *(bf16x8*)&Bpad[row][q * 8] = *(const bf16x8*)&Bw[(size_t)(bn + row) * ldb + k0 + q * 8];
        }
        __syncthreads();
#pragma unroll
        for (int ks = 0; ks < 2; ++ks) {
            bf16x8 a8 = *(const bf16x8*)&Apad[w * 16 + (l & 15)][ks * 32 + (l >> 4) * 8];
#pragma unroll
            for (int nf = 0; nf < 4; ++nf) {
                bf16x8 b8 = *(const bf16x8*)&Bpad[nf * 16 + (l & 15)][ks * 32 + (l >> 4) * 8];
                acc[nf] = __builtin_amdgcn_mfma_f32_16x16x32_bf16(a8, b8, acc[nf], 0, 0, 0);
            }
        }
        __syncthreads();
    }

    int rbase = bm + w * 16 + (l >> 4) * 4;
    int cl = l & 15;
#pragma unroll
    for (int nf = 0; nf < 4; ++nf) {
        int col = bn + nf * 16 + cl;
#pragma unroll
        for (int j = 0; j < 4; ++j) {
            int row = rbase + j;
            if (col < N) {
                int orow = (row & 63) * T_ + (row >> 6);  // t*64+b -> b*T+t
                outF[(size_t)orow * ldo + col] = acc[nf][j] + bias[col];
            }
        }
    }
}

// ===========================================================================
// STEP KERNEL 1 — per-batch (64 blocks x 512 thr) — verified r13, unchanged.
// ===========================================================================
__global__ __launch_bounds__(512) void attn1_k(
    const float* __restrict__ hwp, const float* __restrict__ b2,
    const bf16_t* __restrict__ fW1b, const float* __restrict__ V,
    const float* __restrict__ bV, const bf16_t* __restrict__ F1g,
    const bf16_t* __restrict__ xeb, const float* __restrict__ G1h,
    const float* __restrict__ c1r, float* __restrict__ c1w,
    bf16_t* __restrict__ h1w)
{
    const int b = blockIdx.x, tid = threadIdx.x;
    const int w = tid >> 6, l = tid & 63;
    __shared__ float hw[512];
    __shared__ float sc[64];
    __shared__ float wn[64];
    __shared__ float gsum[2][2048];

    {   // hw reduce over 32 partials (contiguous [b][nb][a] layout)
        float a0 = b2[tid];
        const float* hp = hwp + (size_t)b * 16384 + tid;
#pragma unroll 8
        for (int nb = 0; nb < 32; ++nb) a0 += hp[nb * 512];
        hw[tid] = a0;
    }
    __syncthreads();
    {   // scores (8 waves)
        float hwr[8], Vr[8];
#pragma unroll
        for (int i = 0; i < 8; ++i) { hwr[i] = hw[l * 8 + i]; Vr[i] = V[l * 8 + i]; }
        for (int pq = w; pq < P_; pq += 8) {
            bf16x8 f8 = *(const bf16x8*)&fW1b[(size_t)(b * P_ + pq) * 512 + l * 8];
            float s = 0.f;
#pragma unroll
            for (int i = 0; i < 8; ++i) s += tanhf((float)f8[i] + hwr[i]) * Vr[i];
#pragma unroll
            for (int o = 32; o; o >>= 1) s += __shfl_xor(s, o);
            if (l == 0) sc[pq] = s + bV[0];
        }
    }
    __syncthreads();
    {   // softmax
        float m = -1e30f;
        for (int q = 0; q < P_; ++q) m = fmaxf(m, sc[q]);
        float ss = 0.f;
        for (int q = 0; q < P_; ++q) ss += expf(sc[q] - m);
        if (tid < P_) wn[tid] = expf(sc[tid] - m) / ss;
    }
    __syncthreads();
    {   // g1pre split-P: half h covers rows [h*25, h*25+pn)
        const int h = tid >> 8, th = tid & 255;
        const int p0 = h ? 25 : 0, pn = h ? 24 : 25;
        float acc[8] = {};
        const bf16_t* fg = F1g + ((size_t)b * P_ + p0) * 2048 + th * 8;
        for (int q = 0; q < pn; ++q) {
            bf16x8 f8 = *(const bf16x8*)&fg[(size_t)q * 2048];
            float wq = wn[p0 + q];
#pragma unroll
            for (int i = 0; i < 8; ++i) acc[i] += wq * (float)f8[i];
        }
#pragma unroll
        for (int i = 0; i < 8; ++i) gsum[h][th * 8 + i] = acc[i];
    }
    __syncthreads();
    {   // pw1: one gate-col per thread
        const int d = tid;
        const bf16_t* xb = xeb + (size_t)b * G4;
        const float* gh = G1h + b * 2048;
        float gi = (float)xb[d]        + gsum[0][d]        + gsum[1][d]        + gh[d];
        float gf = (float)xb[512 + d]  + gsum[0][512 + d]  + gsum[1][512 + d]  + gh[512 + d];
        float gg = (float)xb[1024 + d] + gsum[0][1024 + d] + gsum[1][1024 + d] + gh[1024 + d];
        float go = (float)xb[1536 + d] + gsum[0][1536 + d] + gsum[1][1536 + d] + gh[1536 + d];
        int idx = b * 512 + d;
        float cn = sigf(gf) * c1r[idx] + sigf(gi) * tanhf(gg);
        c1w[idx] = cn;
        h1w[idx] = (bf16_t)(sigf(go) * tanhf(cn));
    }
}

// ===========================================================================
// STEP KERNEL 2 — 64 blocks x 512 thr — verified r12/r13, unchanged.
// ===========================================================================
__global__ __launch_bounds__(512) void gate2_k(
    const bf16_t* __restrict__ h1n, const bf16_t* __restrict__ h2r,
    const bf16_t* __restrict__ fp2, const bf16_t* __restrict__ fp1h,
    const bf16_t* __restrict__ W2sp, const float* __restrict__ bsum2,
    const float* __restrict__ c2r, float* __restrict__ c2w,
    bf16_t* __restrict__ h2w, float* __restrict__ G1h, float* __restrict__ hwp)
{
    const int bid = blockIdx.x, tid = threadIdx.x;
    const int w = tid >> 6, l = tid & 63;
    const int l15 = l & 15, koff = (l >> 4) * 8;
    const int mt = w & 3, kh = w >> 2;
    __shared__ float red[2][4][4][256];   // 32 KB
    __shared__ bf16_t h2t[64 * 16];       // 2 KB

    if (bid < 32) {
        const int nb = bid;
        {
            const int arow = mt * 16 + l15;
            const bf16_t* ap = (kh == 0 ? h1n : h2r) + arow * 512 + koff;
            const bf16_t* wp = fp2 + ((size_t)nb * 32 + kh * 16) * 2048 + l * 8;
            f32x4 acc[4] = {};
#pragma unroll
            for (int kf = 0; kf < 16; ++kf) {
                bf16x8 a8 = *(const bf16x8*)&ap[kf * 32];
                const bf16_t* wk = wp + (size_t)kf * 2048;
#pragma unroll
                for (int s = 0; s < 4; ++s) {
                    bf16x8 w8 = *(const bf16x8*)&wk[s * 512];
                    acc[s] = __builtin_amdgcn_mfma_f32_16x16x32_bf16(a8, w8, acc[s], 0, 0, 0);
                }
            }
#pragma unroll
            for (int s = 0; s < 4; ++s) *(f32x4*)&red[kh][mt][s][l * 4] = acc[s];
        }
        __syncthreads();
        if (w < 4) {
            const int d = nb * 16 + l15;
            const int rb = w * 16 + ((l >> 4) << 2);
            f32x4 v[4];
#pragma unroll
            for (int s = 0; s < 4; ++s)
                v[s] = *(const f32x4*)&red[0][w][s][l * 4] + *(const f32x4*)&red[1][w][s][l * 4];
#pragma unroll
            for (int j = 0; j < 4; ++j) {
                int row = rb + j;
                float gi = v[0][j] + bsum2[d];
                float gf = v[1][j] + bsum2[512 + d];
                float gg = v[2][j] + bsum2[1024 + d];
                float go = v[3][j] + bsum2[1536 + d];
                float cn = sigf(gf) * c2r[row * 512 + d] + sigf(gi) * tanhf(gg);
                c2w[row * 512 + d] = cn;
                bf16_t hb = (bf16_t)(sigf(go) * tanhf(cn));
                h2w[row * 512 + d] = hb;
                h2t[row * 16 + l15] = hb;
            }
        }
        __syncthreads();
        {
            bf16x8 a8 = {};
            if ((l >> 4) < 2) a8 = *(const bf16x8*)&h2t[(mt * 16 + l15) * 16 + koff];
            const int row0 = mt * 16 + (l >> 4) * 4;
            for (int q = 0; q < 16; ++q) {
                int nt = kh * 16 + q;
                bf16x8 b8 = *(const bf16x8*)&W2sp[((size_t)(nb * 32 + nt) * 64 + l) * 8];
                f32x4 acc2 = {};
                acc2 = __builtin_amdgcn_mfma_f32_16x16x32_bf16(a8, b8, acc2, 0, 0, 0);
                const int col = nt * 16 + l15;
#pragma unroll
                for (int j = 0; j < 4; ++j)
                    hwp[(size_t)(row0 + j) * 16384 + nb * 512 + col] = acc2[j];
            }
        }
    } else {
        const int nb = bid - 32;
        {
            const int arow = mt * 16 + l15;
            const bf16_t* ap = h1n + arow * 512 + kh * 256 + koff;
            const bf16_t* wp = fp1h + ((size_t)nb * 16 + kh * 8) * 2048 + l * 8;
            f32x4 acc[4] = {};
#pragma unroll
            for (int kf = 0; kf < 8; ++kf) {
                bf16x8 a8 = *(const bf16x8*)&ap[kf * 32];
                const bf16_t* wk = wp + (size_t)kf * 2048;
#pragma unroll
                for (int s = 0; s < 4; ++s) {
                    bf16x8 w8 = *(const bf16x8*)&wk[s * 512];
                    acc[s] = __builtin_amdgcn_mfma_f32_16x16x32_bf16(a8, w8, acc[s], 0, 0, 0);
                }
            }
#pragma unroll
            for (int s = 0; s < 4; ++s) *(f32x4*)&red[kh][mt][s][l * 4] = acc[s];
        }
        __syncthreads();
        if (w < 4) {
            const int d = nb * 16 + l15;
            const int rb = w * 16 + ((l >> 4) << 2);
#pragma unroll
            for (int s = 0; s < 4; ++s) {
                f32x4 v = *(const f32x4*)&red[0][w][s][l * 4] + *(const f32x4*)&red[1][w][s][l * 4];
#pragma unroll
                for (int j = 0; j < 4; ++j)
                    G1h[(rb + j) * 2048 + s * 512 + d] = v[j];
            }
        }
    }
}

// ---------------------------------------------------------------------------
extern "C" void kernel_launch(void* const* d_in, const int* in_sizes, int n_in,
                              void* d_out, int out_size, void* d_ws, size_t ws_size,
                              hipStream_t stream)
{
    const float* features = (const float*)d_in[0];
    const int*   captions = (const int*)d_in[1];
    const float* emb   = (const float*)d_in[2];
    const float* W1    = (const float*)d_in[3];
    const float* b1    = (const float*)d_in[4];
    const float* W2    = (const float*)d_in[5];
    const float* b2    = (const float*)d_in[6];
    const float* V     = (const float*)d_in[7];
    const float* bV    = (const float*)d_in[8];
    const float* W_ih1 = (const float*)d_in[9];
    const float* W_hh1 = (const float*)d_in[10];
    const float* b_ih1 = (const float*)d_in[11];
    const float* b_hh1 = (const float*)d_in[12];
    const float* W_ih2 = (const float*)d_in[13];
    const float* W_hh2 = (const float*)d_in[14];
    const float* b_ih2 = (const float*)d_in[15];
    const float* b_hh2 = (const float*)d_in[16];
    const float* fc_W  = (const float*)d_in[17];
    const float* fc_b  = (const float*)d_in[18];
    float* out = (float*)d_out;

    char* ws = (char*)d_ws;
    size_t off = 0;
    auto alloc = [&](size_t nbytes) {
        char* pp = ws + off;
        off = (off + nbytes + 255) & ~(size_t)255;
        return pp;
    };
    bf16_t* fW1b   = (bf16_t*)alloc(3136L * 512 * 2);    // 3.2 MB
    bf16_t* F1g    = (bf16_t*)alloc(3136L * 2048 * 2);   // 12.8 MB
    bf16_t* W2sp   = (bf16_t*)alloc(32L * 32 * 64 * 8 * 2); // 1.0 MB
    bf16_t* fp1h   = (bf16_t*)alloc(32L * 16 * 2048 * 2);   // 2.1 MB
    bf16_t* fp2    = (bf16_t*)alloc(2048L * 1024 * 2);   // 4.2 MB
    bf16_t* fcWb   = (bf16_t*)alloc((size_t)VPAD * 512 * 2); // 10.5 MB
    bf16_t* xembb  = (bf16_t*)alloc(1920L * 2048 * 2);   // 7.9 MB
    float*  bsum2  = (float*)alloc(2048 * 4);
    float*  hwp    = (float*)alloc(32L * SL * 4);        // 4.0 MB, [b][nb][a]
    float*  G1h    = (float*)alloc(64L * 2048 * 4);      // 0.5 MB
    bf16_t* h1s    = (bf16_t*)alloc((size_t)(T_ + 1) * SL * 2);
    bf16_t* h2s    = (bf16_t*)alloc((size_t)(T_ + 1) * SL * 2);
    float*  c1s    = (float*)alloc(2L * SL * 4);
    float*  c2s    = (float*)alloc(2L * SL * 4);
    // total ~50 MB (< proven 68.5 MB)

    MegaP mp;
    mp.features = features; mp.emb = emb; mp.W1 = W1; mp.b1 = b1; mp.W2 = W2;
    mp.W_ih1 = W_ih1; mp.W_hh1 = W_hh1; mp.W_ih2 = W_ih2; mp.W_hh2 = W_hh2;
    mp.b_ih1 = b_ih1; mp.b_hh1 = b_hh1; mp.b_ih2 = b_ih2; mp.b_hh2 = b_hh2;
    mp.fc_W = fc_W; mp.caps = captions;
    mp.fW1b = fW1b; mp.xembb = xembb; mp.F1g = F1g; mp.W2sp = W2sp;
    mp.fp1h = fp1h; mp.fp2 = fp2; mp.fcWb = fcWb;
    mp.bsum2 = bsum2; mp.hwp = hwp; mp.G1h = G1h;
    mp.c1s0 = c1s; mp.c2s0 = c2s; mp.h1s0 = h1s; mp.h2s0 = h2s;

    mega_k<<<NGEMM + NPREP, 256, 0, stream>>>(mp);

    for (int t = 0; t < T_; ++t) {
        attn1_k<<<B_, 512, 0, stream>>>(
            hwp, b2, fW1b, V, bV, F1g,
            xembb + (size_t)t * B_ * G4, G1h,
            c1s + (size_t)(t & 1) * SL, c1s + (size_t)((t + 1) & 1) * SL,
            h1s + (size_t)(t + 1) * SL);
        gate2_k<<<64, 512, 0, stream>>>(
            h1s + (size_t)(t + 1) * SL, h2s + (size_t)t * SL,
            fp2, fp1h, W2sp, bsum2,
            c2s + (size_t)(t & 1) * SL, c2s + (size_t)((t + 1) & 1) * SL,
            h2s + (size_t)(t + 1) * SL, G1h, hwp);
    }

    // out = h2(1..30) @ fc_W^T + fc_b  (f32 out, row remap t*64+b -> b*T+t)
    mm_fc<<<dim3(VPAD / 64, (T_ * B_) / 64), 256, 0, stream>>>(
        h2s + SL, DEC, fcWb, DEC, fc_b, out, VOCAB, VOCAB, DEC);
}